// Round 4
// baseline (165.937 us; speedup 1.0000x reference)
//
#include <hip/hip_runtime.h>
#include <hip/hip_bf16.h>

// EdgePredictor: out[e] = relu(concat(X[row], X[col]) @ W1 + b1) @ W2 + b2
// Precompute per-node AB[n][256] = {X[n]@W1[:128,:] | X[n]@W1[128:,:]} in f16.
// Per edge: out = relu(A[row] + B[col] + b1) @ W2 + b2.
//
// R4: gemm_ab swaps MFMA operands (A=W-frag, B=X-frag) so D packs 4
// consecutive output cols per lane -> 16 x b64 stores instead of 64 x b16
// scalar scattered stores (the old epilogue was the kernel's top instruction
// class). edge_mlp processes 32 edges/wave with all 16 gather b128s in
// flight before compute (was 8 — gather-latency-bound at VALUBusy 10.7%).

#define EMBED 128

typedef _Float16 half8 __attribute__((ext_vector_type(8)));
typedef _Float16 half4 __attribute__((ext_vector_type(4)));
typedef float floatx4 __attribute__((ext_vector_type(4)));

// --- Kernel 0: fused prep.
// Blocks 0..127: transpose+convert W1 (256x128 f32) -> WT (256x128 f16),
//   WT[j][k] = Wcat[k][j] (Wcat = [W1 top | W1 bottom] per concat split).
// Block 128: idx-mode ballot detect; W2PT[16][128] f16; b1f[128] f16.
__global__ __launch_bounds__(256) void prep(
    const float* __restrict__ W1, const float* __restrict__ W2,
    const float* __restrict__ b1, const int* __restrict__ idx,
    _Float16* __restrict__ WT, _Float16* __restrict__ W2PT,
    _Float16* __restrict__ b1f, int* __restrict__ flag) {
    if (blockIdx.x < 128) {
        __shared__ float lds[16][17];
        const int ty = threadIdx.x >> 4, tx = threadIdx.x & 15;
        const int r0 = (blockIdx.x >> 3) * 16;   // source W1 row tile
        const int c0 = (blockIdx.x & 7) * 16;    // source W1 col tile
        lds[ty][tx] = W1[(r0 + ty) * 128 + c0 + tx];
        __syncthreads();
        const int jbase = c0 + (r0 >= 128 ? 128 : 0);
        const int kbase = r0 & 127;
        WT[(size_t)(jbase + ty) * 128 + kbase + tx] = (_Float16)lds[tx][ty];
    } else {
        const int t = threadIdx.x;
        if (t < 64) {  // int64 layout iff first 64 high words are all zero
            const int hw = idx[2 * t + 1];
            const unsigned long long m = __ballot(hw != 0);
            if (t == 0) *flag = (m == 0ull) ? 1 : 0;
        }
        if (t < 128) b1f[t] = (_Float16)b1[t];
        for (int i = t; i < 2048; i += 256) {  // W2PT[n][k] = n<2 ? W2[k][n] : 0
            const int n = i >> 7, k = i & 127;
            W2PT[i] = (n < 2) ? (_Float16)W2[k * 2 + n] : (_Float16)0.f;
        }
    }
}

// --- Kernel 1: AB = [X | X] @ Wcat via f16 MFMA, operand-swapped.
// M-tile 64 nodes/block, 4 waves, wave w covers output cols [w*64, w*64+64).
// A-operand = W-frags (m-dim = output col), B-operand = X-frags (n-dim = node)
// => D[row=quad*4+r -> col j][col=lane&15 -> node]: 4 consecutive j per lane,
// packed half4 (b64) stores.
__global__ __launch_bounds__(256) void gemm_ab(
    const float* __restrict__ X, const _Float16* __restrict__ WT,
    _Float16* __restrict__ AB, int n_nodes) {
    __shared__ _Float16 xs[64 * 136];  // 17408 B, stride 136 f16
    const int t = threadIdx.x;
    const int mblk = blockIdx.x * 64;

    // Stage: 64 rows x 128 f32, coalesced float4 loads, convert once.
#pragma unroll
    for (int i = 0; i < 8; ++i) {
        const int flat = i * 1024 + t * 4;  // float index in 64x128 tile
        const int row = flat >> 7, col = flat & 127;
        int node = mblk + row;
        if (node > n_nodes - 1) node = n_nodes - 1;  // clamp; never stored
        const float4 v = *(const float4*)(X + (size_t)node * EMBED + col);
        half4 h;
        h[0] = (_Float16)v.x; h[1] = (_Float16)v.y;
        h[2] = (_Float16)v.z; h[3] = (_Float16)v.w;
        *(half4*)(xs + row * 136 + col) = h;
    }
    __syncthreads();

    const int w = t >> 6, lane = t & 63, lm = lane & 15, quad = lane >> 4;

    floatx4 acc[4][4];  // [mf: node tile][jf: col tile]
#pragma unroll
    for (int a = 0; a < 4; ++a)
#pragma unroll
        for (int b = 0; b < 4; ++b)
            acc[a][b] = (floatx4){0.f, 0.f, 0.f, 0.f};

#pragma unroll
    for (int ks = 0; ks < 4; ++ks) {
        const int k0 = ks * 32 + quad * 8;
        half8 xf[4];  // B-operand: B[k][n=lane&15] = Xf16[node mf*16+lm][k]
#pragma unroll
        for (int mf = 0; mf < 4; ++mf)
            xf[mf] = *(const half8*)(xs + (mf * 16 + lm) * 136 + k0);
#pragma unroll
        for (int jf = 0; jf < 4; ++jf) {
            // A-operand: A[m=lane&15 -> col j][k] = WT[j][k]
            const int j = w * 64 + jf * 16 + lm;
            const half8 wf = *(const half8*)(WT + (size_t)j * EMBED + k0);
#pragma unroll
            for (int mf = 0; mf < 4; ++mf)
                acc[mf][jf] = __builtin_amdgcn_mfma_f32_16x16x32_f16(wf, xf[mf], acc[mf][jf], 0, 0, 0);
        }
    }

    // D: col(lane&15) = node within mf-tile, row(quad*4+r) = output col j.
#pragma unroll
    for (int mf = 0; mf < 4; ++mf) {
        const int node = mblk + mf * 16 + lm;
        if (node < n_nodes) {
#pragma unroll
            for (int jf = 0; jf < 4; ++jf) {
                half4 h;
#pragma unroll
                for (int r = 0; r < 4; ++r) h[r] = (_Float16)acc[mf][jf][r];
                *(half4*)(AB + (size_t)node * 256 + w * 64 + jf * 16 + quad * 4) = h;
            }
        }
    }
}

// --- Kernel 2: per-edge MLP, 32 edges/wave (2 MFMA groups), all gathers
// issued before compute. Lane l serves edges ebase+(l&15) and ebase+16+(l&15);
// gathers land directly in MFMA A-layout (A[m=lane&15][k=quad*8+j]).
__global__ __launch_bounds__(256) void edge_mlp(
    const _Float16* __restrict__ AB, const int* __restrict__ eidx,
    const int* __restrict__ flag, const _Float16* __restrict__ b1f,
    const _Float16* __restrict__ W2PT, const float* __restrict__ b2,
    float* __restrict__ out, int n_edges) {
    const int lane = threadIdx.x & 63, lm = lane & 15, quad = lane >> 4;
    const int ebase = (blockIdx.x * 4 + (threadIdx.x >> 6)) * 32;
    if (ebase >= n_edges) return;

    const int mode = *flag;  // wave-uniform
    int e0 = ebase + lm, e1 = ebase + 16 + lm;
    if (e0 > n_edges - 1) e0 = n_edges - 1;  // tail clamp; stores guarded
    if (e1 > n_edges - 1) e1 = n_edges - 1;
    int row0, col0, row1, col1;
    if (mode) {  // int64 layout: low word at int32 index 2*k
        row0 = eidx[2 * (size_t)e0];
        col0 = eidx[2 * ((size_t)n_edges + e0)];
        row1 = eidx[2 * (size_t)e1];
        col1 = eidx[2 * ((size_t)n_edges + e1)];
    } else {
        row0 = eidx[e0];
        col0 = eidx[(size_t)n_edges + e0];
        row1 = eidx[e1];
        col1 = eidx[(size_t)n_edges + e1];
    }

    const _Float16* a0p = AB + (size_t)row0 * 256;
    const _Float16* b0p = AB + (size_t)col0 * 256 + 128;
    const _Float16* a1p = AB + (size_t)row1 * 256;
    const _Float16* b1p = AB + (size_t)col1 * 256 + 128;

    // Issue all 16 gathers up front (each b128: 16 rows x 64B contiguous).
    half8 a0[4], b0[4], a1[4], b1[4];
#pragma unroll
    for (int ks = 0; ks < 4; ++ks) {
        const int k0 = ks * 32 + quad * 8;
        a0[ks] = *(const half8*)(a0p + k0);
        b0[ks] = *(const half8*)(b0p + k0);
        a1[ks] = *(const half8*)(a1p + k0);
        b1[ks] = *(const half8*)(b1p + k0);
    }

    floatx4 acc0 = (floatx4){0.f, 0.f, 0.f, 0.f};
    floatx4 acc1 = (floatx4){0.f, 0.f, 0.f, 0.f};
#pragma unroll
    for (int ks = 0; ks < 4; ++ks) {
        const int k0 = ks * 32 + quad * 8;
        const half8 bi = *(const half8*)(b1f + k0);          // wave-uniform
        const half8 wv = *(const half8*)(W2PT + lm * 128 + k0);
        half8 h0 = a0[ks] + b0[ks] + bi;
        half8 h1 = a1[ks] + b1[ks] + bi;
#pragma unroll
        for (int j = 0; j < 8; ++j) {
            h0[j] = h0[j] > (_Float16)0.f ? h0[j] : (_Float16)0.f;
            h1[j] = h1[j] > (_Float16)0.f ? h1[j] : (_Float16)0.f;
        }
        acc0 = __builtin_amdgcn_mfma_f32_16x16x32_f16(h0, wv, acc0, 0, 0, 0);
        acc1 = __builtin_amdgcn_mfma_f32_16x16x32_f16(h1, wv, acc1, 0, 0, 0);
    }

    if (lm < 2) {
        const float b2v = b2[lm];
#pragma unroll
        for (int r = 0; r < 4; ++r) {
            const int ed0 = ebase + quad * 4 + r;
            const int ed1 = ebase + 16 + quad * 4 + r;
            if (ed0 < n_edges) out[(size_t)ed0 * 2 + lm] = acc0[r] + b2v;
            if (ed1 < n_edges) out[(size_t)ed1 * 2 + lm] = acc1[r] + b2v;
        }
    }
}

extern "C" void kernel_launch(void* const* d_in, const int* in_sizes, int n_in,
                              void* d_out, int out_size, void* d_ws, size_t ws_size,
                              hipStream_t stream) {
    const float* X   = (const float*)d_in[0];
    const int*   idx = (const int*)d_in[1];
    const float* W1  = (const float*)d_in[2];
    const float* b1  = (const float*)d_in[3];
    const float* W2  = (const float*)d_in[4];
    const float* b2  = (const float*)d_in[5];
    float* out = (float*)d_out;

    const int n_nodes = in_sizes[0] / EMBED;   // 100000
    const int n_edges = in_sizes[1] / 2;       // 500000

    // ws: flag @0 | AB @256 (n_nodes*256*2 B) | WT (64KB) | W2PT (4KB) | b1f (256B)
    char* ws = (char*)d_ws;
    int*      flag = (int*)ws;
    _Float16* AB   = (_Float16*)(ws + 256);
    _Float16* WT   = (_Float16*)(ws + 256 + (size_t)n_nodes * 512);
    _Float16* W2PT = WT + 256 * 128;
    _Float16* b1f  = W2PT + 16 * 128;

    prep<<<129, 256, 0, stream>>>(W1, W2, b1, idx, WT, W2PT, b1f, flag);
    gemm_ab<<<(n_nodes + 63) / 64, 256, 0, stream>>>(X, WT, AB, n_nodes);
    edge_mlp<<<(n_edges + 127) / 128, 256, 0, stream>>>(
        AB, idx, flag, b1f, W2PT, b2, out, n_edges);
}

// Round 5
// 153.549 us; speedup vs baseline: 1.0807x; 1.0807x over previous
//
#include <hip/hip_runtime.h>
#include <hip/hip_bf16.h>

// EdgePredictor: out[e] = relu(concat(X[row], X[col]) @ W1 + b1) @ W2 + b2
// Precompute per-node AB[n][256] = {X[n]@W1[:128,:] | X[n]@W1[128:,:]} in f16.
// Per edge: out = relu(A[row] + B[col] + b1) @ W2 + b2.
//
// R5 (single-variable: gemm_ab only): implied gemm_ab cost ~105us vs ~18us
// memory floor. Epilogue was 16 store instrs/wave each scattering 8B over 16
// cache lines at 512B stride (L2 assembles each 64B AB line from 8 partial
// writes). Now: pack D-frags into a padded 64x264 LDS tile, store the 32KB
// node-major region fully coalesced (b128/lane). Grid-stride 2 tiles/block
// so resident blocks overlap each other's stage-barrier drains.

#define EMBED 128

typedef _Float16 half8 __attribute__((ext_vector_type(8)));
typedef _Float16 half4 __attribute__((ext_vector_type(4)));
typedef float floatx4 __attribute__((ext_vector_type(4)));

// --- Kernel 0: fused prep.
// Blocks 0..127: transpose+convert W1 (256x128 f32) -> WT (256x128 f16),
//   WT[j][k] = Wcat[k][j] (Wcat = [W1 top | W1 bottom] per concat split).
// Block 128: idx-mode ballot detect; W2PT[16][128] f16; b1f[128] f16.
__global__ __launch_bounds__(256) void prep(
    const float* __restrict__ W1, const float* __restrict__ W2,
    const float* __restrict__ b1, const int* __restrict__ idx,
    _Float16* __restrict__ WT, _Float16* __restrict__ W2PT,
    _Float16* __restrict__ b1f, int* __restrict__ flag) {
    if (blockIdx.x < 128) {
        __shared__ float lds[16][17];
        const int ty = threadIdx.x >> 4, tx = threadIdx.x & 15;
        const int r0 = (blockIdx.x >> 3) * 16;   // source W1 row tile
        const int c0 = (blockIdx.x & 7) * 16;    // source W1 col tile
        lds[ty][tx] = W1[(r0 + ty) * 128 + c0 + tx];
        __syncthreads();
        const int jbase = c0 + (r0 >= 128 ? 128 : 0);
        const int kbase = r0 & 127;
        WT[(size_t)(jbase + ty) * 128 + kbase + tx] = (_Float16)lds[tx][ty];
    } else {
        const int t = threadIdx.x;
        if (t < 64) {  // int64 layout iff first 64 high words are all zero
            const int hw = idx[2 * t + 1];
            const unsigned long long m = __ballot(hw != 0);
            if (t == 0) *flag = (m == 0ull) ? 1 : 0;
        }
        if (t < 128) b1f[t] = (_Float16)b1[t];
        for (int i = t; i < 2048; i += 256) {  // W2PT[n][k] = n<2 ? W2[k][n] : 0
            const int n = i >> 7, k = i & 127;
            W2PT[i] = (n < 2) ? (_Float16)W2[k * 2 + n] : (_Float16)0.f;
        }
    }
}

// --- Kernel 1: AB = [X | X] @ Wcat via f16 MFMA, operand-swapped
// (A-operand = W-frag so D rows are output cols). Grid-stride over 64-node
// tiles; 4 waves, wave w covers output cols [w*64, w*64+64).
// Epilogue: D-frags -> padded LDS tile -> fully coalesced b128 stores.
__global__ __launch_bounds__(256) void gemm_ab(
    const float* __restrict__ X, const _Float16* __restrict__ WT,
    _Float16* __restrict__ AB, int n_nodes, int n_tiles) {
    __shared__ _Float16 xs[64 * 136];    // 17408 B staging, stride 136
    __shared__ _Float16 outs[64 * 264];  // 33792 B out tile, stride 264
    const int t = threadIdx.x;
    const int w = t >> 6, lane = t & 63, lm = lane & 15, quad = lane >> 4;

    for (int T = blockIdx.x; T < n_tiles; T += gridDim.x) {
        const int mblk = T * 64;

        // Stage: 64 rows x 128 f32, coalesced float4 loads, convert once.
#pragma unroll
        for (int i = 0; i < 8; ++i) {
            const int flat = i * 1024 + t * 4;  // float index in 64x128 tile
            const int row = flat >> 7, col = flat & 127;
            int node = mblk + row;
            if (node > n_nodes - 1) node = n_nodes - 1;  // clamp; never stored
            const float4 v = *(const float4*)(X + (size_t)node * EMBED + col);
            half4 h;
            h[0] = (_Float16)v.x; h[1] = (_Float16)v.y;
            h[2] = (_Float16)v.z; h[3] = (_Float16)v.w;
            *(half4*)(xs + row * 136 + col) = h;
        }
        __syncthreads();

        floatx4 acc[4][4];  // [mf: node tile][jf: col tile]
#pragma unroll
        for (int a = 0; a < 4; ++a)
#pragma unroll
            for (int b = 0; b < 4; ++b)
                acc[a][b] = (floatx4){0.f, 0.f, 0.f, 0.f};

#pragma unroll
        for (int ks = 0; ks < 4; ++ks) {
            const int k0 = ks * 32 + quad * 8;
            half8 xf[4];  // B-operand: B[k][n=lane&15] = Xf16[node mf*16+lm][k]
#pragma unroll
            for (int mf = 0; mf < 4; ++mf)
                xf[mf] = *(const half8*)(xs + (mf * 16 + lm) * 136 + k0);
#pragma unroll
            for (int jf = 0; jf < 4; ++jf) {
                // A-operand: A[m=lane&15 -> col j][k] = WT[j][k]
                const int j = w * 64 + jf * 16 + lm;
                const half8 wf = *(const half8*)(WT + (size_t)j * EMBED + k0);
#pragma unroll
                for (int mf = 0; mf < 4; ++mf)
                    acc[mf][jf] = __builtin_amdgcn_mfma_f32_16x16x32_f16(wf, xf[mf], acc[mf][jf], 0, 0, 0);
            }
        }

        // Pack D into LDS out tile: node-major [local node][j], stride 264.
        // D: col(lane&15) = node within mf-tile, row(quad*4+r) = output col j.
#pragma unroll
        for (int mf = 0; mf < 4; ++mf) {
#pragma unroll
            for (int jf = 0; jf < 4; ++jf) {
                half4 h;
#pragma unroll
                for (int r = 0; r < 4; ++r) h[r] = (_Float16)acc[mf][jf][r];
                *(half4*)(outs + (mf * 16 + lm) * 264 + w * 64 + jf * 16 + quad * 4) = h;
            }
        }
        __syncthreads();

        // Coalesced store: 64 nodes x 512 B contiguous in AB (node-major).
#pragma unroll
        for (int i = 0; i < 8; ++i) {
            const int idx8 = i * 256 + t;         // half8 index in 64x256 tile
            const int node = idx8 >> 5, jj = idx8 & 31;
            if (mblk + node < n_nodes)
                *(half8*)(AB + (size_t)(mblk + node) * 256 + jj * 8) =
                    *(const half8*)(outs + node * 264 + jj * 8);
        }
        // Loop-top __syncthreads separates these outs reads / xs writes from
        // the next tile's outs writes / xs reads.
    }
}

// --- Kernel 2: per-edge MLP, 32 edges/wave (2 MFMA groups), all gathers
// issued before compute. Lane l serves edges ebase+(l&15) and ebase+16+(l&15);
// gathers land directly in MFMA A-layout (A[m=lane&15][k=quad*8+j]).
__global__ __launch_bounds__(256) void edge_mlp(
    const _Float16* __restrict__ AB, const int* __restrict__ eidx,
    const int* __restrict__ flag, const _Float16* __restrict__ b1f,
    const _Float16* __restrict__ W2PT, const float* __restrict__ b2,
    float* __restrict__ out, int n_edges) {
    const int lane = threadIdx.x & 63, lm = lane & 15, quad = lane >> 4;
    const int ebase = (blockIdx.x * 4 + (threadIdx.x >> 6)) * 32;
    if (ebase >= n_edges) return;

    const int mode = *flag;  // wave-uniform
    int e0 = ebase + lm, e1 = ebase + 16 + lm;
    if (e0 > n_edges - 1) e0 = n_edges - 1;  // tail clamp; stores guarded
    if (e1 > n_edges - 1) e1 = n_edges - 1;
    int row0, col0, row1, col1;
    if (mode) {  // int64 layout: low word at int32 index 2*k
        row0 = eidx[2 * (size_t)e0];
        col0 = eidx[2 * ((size_t)n_edges + e0)];
        row1 = eidx[2 * (size_t)e1];
        col1 = eidx[2 * ((size_t)n_edges + e1)];
    } else {
        row0 = eidx[e0];
        col0 = eidx[(size_t)n_edges + e0];
        row1 = eidx[e1];
        col1 = eidx[(size_t)n_edges + e1];
    }

    const _Float16* a0p = AB + (size_t)row0 * 256;
    const _Float16* b0p = AB + (size_t)col0 * 256 + 128;
    const _Float16* a1p = AB + (size_t)row1 * 256;
    const _Float16* b1p = AB + (size_t)col1 * 256 + 128;

    // Issue all 16 gathers up front (each b128: 16 rows x 64B contiguous).
    half8 a0[4], b0[4], a1[4], b1[4];
#pragma unroll
    for (int ks = 0; ks < 4; ++ks) {
        const int k0 = ks * 32 + quad * 8;
        a0[ks] = *(const half8*)(a0p + k0);
        b0[ks] = *(const half8*)(b0p + k0);
        a1[ks] = *(const half8*)(a1p + k0);
        b1[ks] = *(const half8*)(b1p + k0);
    }

    floatx4 acc0 = (floatx4){0.f, 0.f, 0.f, 0.f};
    floatx4 acc1 = (floatx4){0.f, 0.f, 0.f, 0.f};
#pragma unroll
    for (int ks = 0; ks < 4; ++ks) {
        const int k0 = ks * 32 + quad * 8;
        const half8 bi = *(const half8*)(b1f + k0);          // wave-uniform
        const half8 wv = *(const half8*)(W2PT + lm * 128 + k0);
        half8 h0 = a0[ks] + b0[ks] + bi;
        half8 h1 = a1[ks] + b1[ks] + bi;
#pragma unroll
        for (int j = 0; j < 8; ++j) {
            h0[j] = h0[j] > (_Float16)0.f ? h0[j] : (_Float16)0.f;
            h1[j] = h1[j] > (_Float16)0.f ? h1[j] : (_Float16)0.f;
        }
        acc0 = __builtin_amdgcn_mfma_f32_16x16x32_f16(h0, wv, acc0, 0, 0, 0);
        acc1 = __builtin_amdgcn_mfma_f32_16x16x32_f16(h1, wv, acc1, 0, 0, 0);
    }

    if (lm < 2) {
        const float b2v = b2[lm];
#pragma unroll
        for (int r = 0; r < 4; ++r) {
            const int ed0 = ebase + quad * 4 + r;
            const int ed1 = ebase + 16 + quad * 4 + r;
            if (ed0 < n_edges) out[(size_t)ed0 * 2 + lm] = acc0[r] + b2v;
            if (ed1 < n_edges) out[(size_t)ed1 * 2 + lm] = acc1[r] + b2v;
        }
    }
}

extern "C" void kernel_launch(void* const* d_in, const int* in_sizes, int n_in,
                              void* d_out, int out_size, void* d_ws, size_t ws_size,
                              hipStream_t stream) {
    const float* X   = (const float*)d_in[0];
    const int*   idx = (const int*)d_in[1];
    const float* W1  = (const float*)d_in[2];
    const float* b1  = (const float*)d_in[3];
    const float* W2  = (const float*)d_in[4];
    const float* b2  = (const float*)d_in[5];
    float* out = (float*)d_out;

    const int n_nodes = in_sizes[0] / EMBED;   // 100000
    const int n_edges = in_sizes[1] / 2;       // 500000

    // ws: flag @0 | AB @256 (n_nodes*256*2 B) | WT (64KB) | W2PT (4KB) | b1f (256B)
    char* ws = (char*)d_ws;
    int*      flag = (int*)ws;
    _Float16* AB   = (_Float16*)(ws + 256);
    _Float16* WT   = (_Float16*)(ws + 256 + (size_t)n_nodes * 512);
    _Float16* W2PT = WT + 256 * 128;
    _Float16* b1f  = W2PT + 16 * 128;

    const int n_tiles = (n_nodes + 63) / 64;   // 1563

    prep<<<129, 256, 0, stream>>>(W1, W2, b1, idx, WT, W2PT, b1f, flag);
    gemm_ab<<<782, 256, 0, stream>>>(X, WT, AB, n_nodes, n_tiles);
    edge_mlp<<<(n_edges + 127) / 128, 256, 0, stream>>>(
        AB, idx, flag, b1f, W2PT, b2, out, n_edges);
}